// Round 5
// baseline (871.686 us; speedup 1.0000x reference)
//
#include <hip/hip_runtime.h>

#define HIDC 128
#define NGRAPH 64
#define EPSV 1e-5f
#define SLICES 16

typedef __attribute__((ext_vector_type(8))) short bf16x8;
typedef __attribute__((ext_vector_type(4))) float f32x4;

__device__ inline uint bf16_rne(float f) {
    uint u = __float_as_uint(f);
    return (u + 0x7fffu + ((u >> 16) & 1u)) >> 16;
}
__device__ inline uint pack2(float a, float b) { return bf16_rne(a) | (bf16_rne(b) << 16); }
__device__ inline float blo(uint v) { return __uint_as_float(v << 16); }
__device__ inline float bhi(uint v) { return __uint_as_float(v & 0xffff0000u); }

// ---------------- CSR build ----------------

__global__ void k_count(const int* __restrict__ ei, int E, int* __restrict__ cnt) {
    int e = blockIdx.x * blockDim.x + threadIdx.x;
    if (e < E) atomicAdd(&cnt[ei[E + e]], 1);
}

__global__ void k_scan1(const int* __restrict__ cnt, int* __restrict__ rp,
                        int* __restrict__ partial, int N) {
    const int tid = threadIdx.x;
    int base = blockIdx.x * 2048 + tid * 8;
    int v[8], pre[8];
    int tot = 0;
#pragma unroll
    for (int j = 0; j < 8; j++) {
        int idx = base + j;
        v[j] = (idx < N) ? cnt[idx] : 0;
        pre[j] = tot; tot += v[j];
    }
    __shared__ int ls[256];
    ls[tid] = tot; __syncthreads();
    for (int off = 1; off < 256; off <<= 1) {
        int add = (tid >= off) ? ls[tid - off] : 0;
        __syncthreads();
        ls[tid] += add;
        __syncthreads();
    }
    int excl = ls[tid] - tot;
#pragma unroll
    for (int j = 0; j < 8; j++) {
        int idx = base + j;
        if (idx < N) rp[idx] = excl + pre[j];
    }
    if (tid == 255) partial[blockIdx.x] = ls[255];
}

__global__ void k_scan2(const int* __restrict__ partial, int* __restrict__ offs, int NP) {
    int tid = threadIdx.x;
    int v = (tid < NP) ? partial[tid] : 0;
    int x = v;
    for (int off = 1; off < 64; off <<= 1) {
        int y = __shfl_up(x, off);
        if (tid >= off) x += y;
    }
    if (tid < NP) offs[tid] = x - v;
}

__global__ void k_scan3(int* __restrict__ rp, int* __restrict__ cursor,
                        const int* __restrict__ offs, const int* __restrict__ cnt,
                        float* __restrict__ dinv, int N, int E) {
    int i = blockIdx.x * blockDim.x + threadIdx.x;
    if (i < N) {
        int v = rp[i] + offs[i >> 11];
        rp[i] = v; cursor[i] = v;
        dinv[i] = rsqrtf((float)(cnt[i] + 1));   // +1 self loop
    }
    if (i == 0) rp[N] = E;
}

__global__ void k_fill(const int* __restrict__ ei, int E, const float* __restrict__ dinv,
                       int* __restrict__ cursor, int2* __restrict__ edata) {
    int e = blockIdx.x * blockDim.x + threadIdx.x;
    if (e >= E) return;
    int s = ei[e], d = ei[E + e];
    int p = atomicAdd(&cursor[d], 1);
    edata[p] = make_int2(s, __float_as_int(dinv[s] * dinv[d]));
}

// ---------------- W prep: fp32 [k][n] -> bf16 swizzled [n][k] (global) ----------------

__global__ void k_prepW(const float* __restrict__ W1, const float* __restrict__ W2,
                        const float* __restrict__ W3, ushort* __restrict__ Wp) {
    int b = blockIdx.x;
    const float* W = (b == 0) ? W1 : (b == 1) ? W2 : W3;
    char* dst = (char*)(Wp + b * 128 * 128);
    for (int idx = threadIdx.x; idx < 128 * 64; idx += 256) {
        int n = idx & 127, k2 = idx >> 7;
        float w0 = W[(2 * k2) * 128 + n];
        float w1 = W[(2 * k2 + 1) * 128 + n];
        int byte = (n << 8) + ((k2 << 2) ^ ((n & 7) << 4));
        *(uint*)(dst + byte) = pack2(w0, w1);
    }
}

// ---------------- layer 0: aggregate x (4ch), then transform+LN ----------------

__global__ void __launch_bounds__(256) k_agg_x(
    const float* __restrict__ x, const int2* __restrict__ edata,
    const int* __restrict__ rp, const float* __restrict__ dinv,
    float* __restrict__ ax, int N)
{
    int tid = threadIdx.x;
    int ch = tid & 3, es = (tid >> 2) & 3;
    int node = blockIdx.x * 16 + (tid >> 4);
    if (node >= N) return;
    int e0 = rp[node], e1 = rp[node + 1];
    float acc = 0.f;
    for (int e = e0 + es; e < e1; e += 4) {
        int2 ed = edata[e];
        acc = fmaf(__int_as_float(ed.y), x[(size_t)ed.x * 4 + ch], acc);
    }
    acc += __shfl_xor(acc, 4);
    acc += __shfl_xor(acc, 8);
    if (es == 0) {
        float di = dinv[node];
        acc = fmaf(di * di, x[(size_t)node * 4 + ch], acc);
        ax[(size_t)node * 4 + ch] = acc;
    }
}

__global__ void __launch_bounds__(256) k_l0_ln(
    const float* __restrict__ ax, const float* __restrict__ W0,
    const float* __restrict__ b0, const float* __restrict__ g0,
    const float* __restrict__ be0, uint* __restrict__ hA, int N)
{
    __shared__ float s[896];
    int tid = threadIdx.x;
    for (int i = tid; i < 896; i += 256) {
        float v;
        if (i < 512) v = W0[i];
        else if (i < 640) v = b0[i - 512];
        else if (i < 768) v = g0[i - 640];
        else v = be0[i - 768];
        s[i] = v;
    }
    __syncthreads();
    int lane = tid & 63;
    int node = blockIdx.x * 4 + (tid >> 6);
    if (node >= N) return;
    float4 a = *(const float4*)&ax[(size_t)node * 4];
    int c0 = 2 * lane, c1 = c0 + 1;
    float v0 = a.x * s[c0] + a.y * s[128 + c0] + a.z * s[256 + c0] + a.w * s[384 + c0] + s[512 + c0];
    float v1 = a.x * s[c1] + a.y * s[128 + c1] + a.z * s[256 + c1] + a.w * s[384 + c1] + s[512 + c1];
    v0 = fmaxf(v0, 0.f); v1 = fmaxf(v1, 0.f);
    float s1 = v0 + v1, s2 = v0 * v0 + v1 * v1;
#pragma unroll
    for (int off = 32; off; off >>= 1) { s1 += __shfl_xor(s1, off); s2 += __shfl_xor(s2, off); }
    float mu = s1 * (1.f / 128.f), var = s2 * (1.f / 128.f) - mu * mu;
    float r = rsqrtf(var + EPSV);
    float o0 = (v0 - mu) * r * s[640 + c0] + s[768 + c0];
    float o1 = (v1 - mu) * r * s[640 + c1] + s[768 + c1];
    hA[(size_t)node * 64 + lane] = pack2(o0, o1);
}

// ---------------- fused: agg(h) -> @W -> +b -> relu -> LN -> out ----------------
// Uses agg(h@W) == (agg h)@W. 64 nodes/block, 4 waves; wave gathers 16 nodes
// into a swizzled LDS tile, then MFMAs its own 16-row m-tile against W from
// global (L2-resident, pre-swizzled), then LN on C-fragments.

__global__ void __launch_bounds__(256) k_fused(
    const uint* __restrict__ tmp,   // N x 64 (bf16x2) gather table
    const int2* __restrict__ edata, const int* __restrict__ rp,
    const float* __restrict__ dinv, const ushort* __restrict__ Wp,
    const float* __restrict__ bias, const float* __restrict__ gamma,
    const float* __restrict__ beta, ushort* __restrict__ outp, int N)
{
    __shared__ char Asw[64 * 256];   // 16 KB [row][256B], XOR-swizzled
    int tid = threadIdx.x;
    int wv = tid >> 6, lane = tid & 63;
    int nbase = blockIdx.x * 64 + wv * 16;

    // phase A: gather
    for (int j = 0; j < 16; ++j) {
        int node = nbase + j;
        float ax = 0.f, ay = 0.f;
        if (node < N) {
            float di = dinv[node];
            uint v = tmp[(size_t)node * 64 + lane];
            ax = di * di * blo(v); ay = di * di * bhi(v);
            int e0 = rp[node], e1 = rp[node + 1];
            int e = e0;
            for (; e + 4 <= e1; e += 4) {
                long long p0 = __builtin_nontemporal_load((const long long*)&edata[e]);
                long long p1 = __builtin_nontemporal_load((const long long*)&edata[e + 1]);
                long long p2 = __builtin_nontemporal_load((const long long*)&edata[e + 2]);
                long long p3 = __builtin_nontemporal_load((const long long*)&edata[e + 3]);
                uint v0 = tmp[(size_t)(int)p0 * 64 + lane];
                uint v1 = tmp[(size_t)(int)p1 * 64 + lane];
                uint v2 = tmp[(size_t)(int)p2 * 64 + lane];
                uint v3 = tmp[(size_t)(int)p3 * 64 + lane];
                float n0 = __int_as_float((int)(p0 >> 32));
                float n1 = __int_as_float((int)(p1 >> 32));
                float n2 = __int_as_float((int)(p2 >> 32));
                float n3 = __int_as_float((int)(p3 >> 32));
                ax = fmaf(n0, blo(v0), ax); ay = fmaf(n0, bhi(v0), ay);
                ax = fmaf(n1, blo(v1), ax); ay = fmaf(n1, bhi(v1), ay);
                ax = fmaf(n2, blo(v2), ax); ay = fmaf(n2, bhi(v2), ay);
                ax = fmaf(n3, blo(v3), ax); ay = fmaf(n3, bhi(v3), ay);
            }
            for (; e < e1; ++e) {
                long long p0 = __builtin_nontemporal_load((const long long*)&edata[e]);
                uint v0 = tmp[(size_t)(int)p0 * 64 + lane];
                float n0 = __int_as_float((int)(p0 >> 32));
                ax = fmaf(n0, blo(v0), ax); ay = fmaf(n0, bhi(v0), ay);
            }
        }
        int row = wv * 16 + j;
        *(uint*)(Asw + row * 256 + ((lane * 4) ^ ((row & 7) << 4))) = pack2(ax, ay);
    }

    // preload LN params for this lane's columns
    int m = lane & 15, g = lane >> 4;
    float bcol[8], gcol[8], becol[8];
#pragma unroll
    for (int nt = 0; nt < 8; ++nt) {
        int c = m + nt * 16;
        bcol[nt] = bias[c]; gcol[nt] = gamma[c]; becol[nt] = beta[c];
    }
    __syncthreads();

    // phase B: MFMA — wave's m-tile = its own 16 rows
    bf16x8 a[4];
    int arow = wv * 16 + m;
    int aswz = (arow & 7) << 4;
#pragma unroll
    for (int kk = 0; kk < 4; ++kk)
        a[kk] = *(const bf16x8*)(Asw + arow * 256 + ((kk * 64 + g * 16) ^ aswz));

    f32x4 acc[8];
#pragma unroll
    for (int nt = 0; nt < 8; ++nt) acc[nt] = (f32x4){0.f, 0.f, 0.f, 0.f};

#pragma unroll
    for (int nt = 0; nt < 8; ++nt) {
        int n = m + nt * 16;
        const char* wb = (const char*)Wp + (n << 8);
        int swz = (n & 7) << 4;
#pragma unroll
        for (int kk = 0; kk < 4; ++kk) {
            bf16x8 b = *(const bf16x8*)(wb + ((kk * 64 + g * 16) ^ swz));
            acc[nt] = __builtin_amdgcn_mfma_f32_16x16x32_bf16(a[kk], b, acc[nt], 0, 0, 0);
        }
    }

    // phase C: bias+relu+LN per output row (row = g*4+q within tile), write
#pragma unroll
    for (int q = 0; q < 4; ++q) {
        float vals[8];
        float s1 = 0.f, s2 = 0.f;
#pragma unroll
        for (int nt = 0; nt < 8; ++nt) {
            float v = fmaxf(acc[nt][q] + bcol[nt], 0.f);
            vals[nt] = v; s1 += v; s2 += v * v;
        }
#pragma unroll
        for (int off = 8; off; off >>= 1) { s1 += __shfl_xor(s1, off); s2 += __shfl_xor(s2, off); }
        float mu = s1 * (1.f / 128.f), var = s2 * (1.f / 128.f) - mu * mu;
        float r = rsqrtf(var + EPSV);
        int orow = nbase + g * 4 + q;
        if (orow < N) {
            ushort* op = outp + (size_t)orow * 128;
#pragma unroll
            for (int nt = 0; nt < 8; ++nt)
                op[m + nt * 16] = (ushort)bf16_rne((vals[nt] - mu) * r * gcol[nt] + becol[nt]);
        }
    }
}

// ---------------- pooling (bf16 input) ----------------

__global__ void __launch_bounds__(64) k_pool(
    const uint* __restrict__ h, const int* __restrict__ batch,
    float* __restrict__ featsum, float* __restrict__ cntg, int N)
{
    int g = blockIdx.x / SLICES, s = blockIdx.x % SLICES;
    int lane = threadIdx.x;
    int lo = 0, hi = N;
    while (lo < hi) { int m = (lo + hi) >> 1; if (batch[m] < g) lo = m + 1; else hi = m; }
    int start = lo;
    hi = N;
    while (lo < hi) { int m = (lo + hi) >> 1; if (batch[m] < g + 1) lo = m + 1; else hi = m; }
    int end = lo;
    int len = end - start;
    if (s == 0 && lane == 0) cntg[g] = (float)len;
    int per = (len + SLICES - 1) / SLICES;
    int a = start + s * per, b = min(a + per, end);
    float accx = 0.f, accy = 0.f;
    for (int i = a; i < b; ++i) {
        uint v = h[(size_t)i * 64 + lane];
        accx += blo(v); accy += bhi(v);
    }
    atomicAdd(&featsum[g * 128 + 2 * lane], accx);
    atomicAdd(&featsum[g * 128 + 2 * lane + 1], accy);
}

// ---------------- FC head (fp32) ----------------

__global__ void __launch_bounds__(256) k_fc1(const float* __restrict__ featsum,
        const float* __restrict__ cntg, const float* __restrict__ W,
        const float* __restrict__ b, float* __restrict__ z1) {
    int g = blockIdx.x, tid = threadIdx.x;
    __shared__ float fr[128];
    if (tid < 128) fr[tid] = featsum[g * 128 + tid] / fmaxf(cntg[g], 1.f);
    __syncthreads();
    float acc[4];
#pragma unroll
    for (int j = 0; j < 4; j++) acc[j] = b[tid + 256 * j];
    for (int k = 0; k < 128; ++k) {
        float f = fr[k];
#pragma unroll
        for (int j = 0; j < 4; j++) acc[j] = fmaf(f, W[k * 1024 + tid + 256 * j], acc[j]);
    }
    float s1 = 0.f, s2 = 0.f;
#pragma unroll
    for (int j = 0; j < 4; j++) { s1 += acc[j]; s2 += acc[j] * acc[j]; }
    for (int off = 32; off; off >>= 1) { s1 += __shfl_xor(s1, off); s2 += __shfl_xor(s2, off); }
    __shared__ float red[8];
    int w = tid >> 6;
    if ((tid & 63) == 0) { red[w] = s1; red[w + 4] = s2; }
    __syncthreads();
    s1 = red[0] + red[1] + red[2] + red[3];
    s2 = red[4] + red[5] + red[6] + red[7];
    float mu = s1 * (1.f / 1024.f), var = s2 * (1.f / 1024.f) - mu * mu;
    float r = rsqrtf(var + EPSV);
#pragma unroll
    for (int j = 0; j < 4; j++)
        z1[g * 1024 + tid + 256 * j] = fmaxf((acc[j] - mu) * r, 0.f);
}

__global__ void __launch_bounds__(256) k_fc2(const float* __restrict__ z1,
        const float* __restrict__ W, const float* __restrict__ b, float* __restrict__ z2) {
    int g = blockIdx.x, tid = threadIdx.x;
    __shared__ float zr[1024];
    for (int i = tid; i < 1024; i += 256) zr[i] = z1[g * 1024 + i];
    __syncthreads();
    float acc = b[tid];
#pragma unroll 8
    for (int k = 0; k < 1024; ++k) acc = fmaf(zr[k], W[k * 256 + tid], acc);
    float s1 = acc, s2 = acc * acc;
    for (int off = 32; off; off >>= 1) { s1 += __shfl_xor(s1, off); s2 += __shfl_xor(s2, off); }
    __shared__ float red[8];
    int w = tid >> 6;
    if ((tid & 63) == 0) { red[w] = s1; red[w + 4] = s2; }
    __syncthreads();
    s1 = red[0] + red[1] + red[2] + red[3];
    s2 = red[4] + red[5] + red[6] + red[7];
    float mu = s1 * (1.f / 256.f), var = s2 * (1.f / 256.f) - mu * mu;
    float r = rsqrtf(var + EPSV);
    z2[g * 256 + tid] = fmaxf((acc - mu) * r, 0.f);
}

__global__ void k_fc3(const float* __restrict__ z2, const float* __restrict__ W,
                      const float* __restrict__ b, float* __restrict__ out) {
    int t = threadIdx.x;
    int g = t >> 2, o = t & 3;
    float acc = b[o];
#pragma unroll 8
    for (int k = 0; k < 256; ++k) acc = fmaf(z2[g * 256 + k], W[k * 4 + o], acc);
    out[t] = acc;
}

// ---------------- launch ----------------

extern "C" void kernel_launch(void* const* d_in, const int* in_sizes, int n_in,
                              void* d_out, int out_size, void* d_ws, size_t ws_size,
                              hipStream_t stream) {
    const float* x    = (const float*)d_in[0];
    const int*   ei   = (const int*)d_in[1];
    const int*   batch= (const int*)d_in[2];
    const float* Wl[4]  = { (const float*)d_in[3], (const float*)d_in[7],  (const float*)d_in[11], (const float*)d_in[15] };
    const float* bl[4]  = { (const float*)d_in[4], (const float*)d_in[8],  (const float*)d_in[12], (const float*)d_in[16] };
    const float* gl[4]  = { (const float*)d_in[5], (const float*)d_in[9],  (const float*)d_in[13], (const float*)d_in[17] };
    const float* bel[4] = { (const float*)d_in[6], (const float*)d_in[10], (const float*)d_in[14], (const float*)d_in[18] };
    const float* fcW1 = (const float*)d_in[19];
    const float* fcb1 = (const float*)d_in[20];
    const float* fcW2 = (const float*)d_in[21];
    const float* fcb2 = (const float*)d_in[22];
    const float* fcW3 = (const float*)d_in[23];
    const float* fcb3 = (const float*)d_in[24];
    float* out = (float*)d_out;

    const int N = in_sizes[2];
    const int E = in_sizes[1] / 2;

    char* w = (char*)d_ws;
    auto alloc = [&](size_t bytes) -> char* {
        char* p = w; w += (bytes + 255) & ~(size_t)255; return p;
    };
    uint*   hA      = (uint*)  alloc((size_t)N * 64 * 4);   // bf16 N x 128
    uint*   hB      = (uint*)  alloc((size_t)N * 64 * 4);
    float*  ax      = (float*) alloc((size_t)N * 4 * 4);
    int2*   edata   = (int2*)  alloc((size_t)E * 8);
    int*    rp      = (int*)   alloc((size_t)(N + 1) * 4);
    int*    cursor  = (int*)   alloc((size_t)N * 4);
    int*    cntI    = (int*)   alloc((size_t)N * 4);
    float*  dinv    = (float*) alloc((size_t)N * 4);
    int*    partial = (int*)   alloc(64 * 4);
    int*    offs    = (int*)   alloc(64 * 4);
    ushort* Wp      = (ushort*)alloc(3 * 128 * 128 * 2);
    float*  featsum = (float*) alloc(NGRAPH * HIDC * 4);
    float*  cntg    = (float*) alloc(NGRAPH * 4);
    float*  z1      = (float*) alloc(NGRAPH * 1024 * 4);
    float*  z2      = (float*) alloc(NGRAPH * 256 * 4);

    const int NCH = (N + 2047) / 2048;

    hipMemsetAsync(cntI, 0, (size_t)N * 4, stream);
    hipMemsetAsync(featsum, 0, NGRAPH * HIDC * 4, stream);

    int egrid = (E + 255) / 256;
    int ngrid = (N + 255) / 256;

    k_count<<<egrid, 256, 0, stream>>>(ei, E, cntI);
    k_scan1<<<NCH, 256, 0, stream>>>(cntI, rp, partial, N);
    k_scan2<<<1, 64, 0, stream>>>(partial, offs, NCH);
    k_scan3<<<ngrid, 256, 0, stream>>>(rp, cursor, offs, cntI, dinv, N, E);
    k_fill<<<egrid, 256, 0, stream>>>(ei, E, dinv, cursor, edata);
    k_prepW<<<3, 256, 0, stream>>>(Wl[1], Wl[2], Wl[3], Wp);

    // layer 0: agg(x) then transform+bias+relu+LN  -> hA
    k_agg_x<<<(N + 15) / 16, 256, 0, stream>>>(x, edata, rp, dinv, ax, N);
    k_l0_ln<<<(N + 3) / 4, 256, 0, stream>>>(ax, Wl[0], bl[0], gl[0], bel[0], hA, N);

    // layers 1..3: fused agg -> @W -> bias -> relu -> LN (ping-pong hA/hB)
    const int fgrid = (N + 63) / 64;
    uint* tin = hA;
    uint* tout = hB;
    for (int L = 1; L < 4; ++L) {
        k_fused<<<fgrid, 256, 0, stream>>>(
            tin, edata, rp, dinv, Wp + (L - 1) * 128 * 128,
            bl[L], gl[L], bel[L], (ushort*)tout, N);
        uint* t = tin; tin = tout; tout = t;
    }
    // after 3 layers, result is in `tin` (hB)

    k_pool<<<NGRAPH * SLICES, 64, 0, stream>>>(tin, batch, featsum, cntg, N);
    k_fc1<<<NGRAPH, 256, 0, stream>>>(featsum, cntg, fcW1, fcb1, z1);
    k_fc2<<<NGRAPH, 256, 0, stream>>>(z1, fcW2, fcb2, z2);
    k_fc3<<<1, 256, 0, stream>>>(z2, fcW3, fcb3, out);
}

// Round 6
// 653.973 us; speedup vs baseline: 1.3329x; 1.3329x over previous
//
#include <hip/hip_runtime.h>

#define HIDC 128
#define NGRAPH 64
#define EPSV 1e-5f
#define SLICES 16

typedef __attribute__((ext_vector_type(8))) short bf16x8;
typedef __attribute__((ext_vector_type(4))) float f32x4;

__device__ inline uint bf16_rne(float f) {
    uint u = __float_as_uint(f);
    return (u + 0x7fffu + ((u >> 16) & 1u)) >> 16;
}
__device__ inline uint pack2(float a, float b) { return bf16_rne(a) | (bf16_rne(b) << 16); }
__device__ inline float blo(uint v) { return __uint_as_float(v << 16); }
__device__ inline float bhi(uint v) { return __uint_as_float(v & 0xffff0000u); }

// ---------------- CSR build ----------------

__global__ void k_count(const int* __restrict__ ei, int E, int* __restrict__ cnt) {
    int e = blockIdx.x * blockDim.x + threadIdx.x;
    if (e < E) atomicAdd(&cnt[ei[E + e]], 1);
}

__global__ void k_scan1(const int* __restrict__ cnt, int* __restrict__ rp,
                        int* __restrict__ partial, int N) {
    const int tid = threadIdx.x;
    int base = blockIdx.x * 2048 + tid * 8;
    int v[8], pre[8];
    int tot = 0;
#pragma unroll
    for (int j = 0; j < 8; j++) {
        int idx = base + j;
        v[j] = (idx < N) ? cnt[idx] : 0;
        pre[j] = tot; tot += v[j];
    }
    __shared__ int ls[256];
    ls[tid] = tot; __syncthreads();
    for (int off = 1; off < 256; off <<= 1) {
        int add = (tid >= off) ? ls[tid - off] : 0;
        __syncthreads();
        ls[tid] += add;
        __syncthreads();
    }
    int excl = ls[tid] - tot;
#pragma unroll
    for (int j = 0; j < 8; j++) {
        int idx = base + j;
        if (idx < N) rp[idx] = excl + pre[j];
    }
    if (tid == 255) partial[blockIdx.x] = ls[255];
}

// scan of 2048-chunk partials folded in: each block sums partial[0..chunk)
// (NCH <= 64 for N <= 131072)
__global__ void k_scan3(int* __restrict__ rp, int* __restrict__ cursor,
                        const int* __restrict__ partial, const int* __restrict__ cnt,
                        float* __restrict__ dinv, int N, int E, int NCH) {
    __shared__ int soff;
    int tid = threadIdx.x;
    int chunk = blockIdx.x >> 3;              // 2048 / 256
    if (tid < 64) {
        int v = (tid < NCH && tid < chunk) ? partial[tid] : 0;
        for (int off = 1; off < 64; off <<= 1) v += __shfl_xor(v, off);
        if (tid == 0) soff = v;
    }
    __syncthreads();
    int i = blockIdx.x * blockDim.x + tid;
    if (i < N) {
        int v = rp[i] + soff;
        rp[i] = v; cursor[i] = v;
        dinv[i] = rsqrtf((float)(cnt[i] + 1));   // +1 self loop
    }
    if (i == 0) rp[N] = E;
}

__global__ void k_fill(const int* __restrict__ ei, int E, const float* __restrict__ dinv,
                       int* __restrict__ cursor, int2* __restrict__ edata) {
    int e = blockIdx.x * blockDim.x + threadIdx.x;
    if (e >= E) return;
    int s = ei[e], d = ei[E + e];
    int p = atomicAdd(&cursor[d], 1);
    edata[p] = make_int2(s, __float_as_int(dinv[s] * dinv[d]));
}

// ---------------- W prep: fp32 [k][n] -> bf16 swizzled [n][k] (global) ----------------

__global__ void k_prepW(const float* __restrict__ W1, const float* __restrict__ W2,
                        const float* __restrict__ W3, ushort* __restrict__ Wp) {
    int b = blockIdx.x;
    const float* W = (b == 0) ? W1 : (b == 1) ? W2 : W3;
    char* dst = (char*)(Wp + b * 128 * 128);
    for (int idx = threadIdx.x; idx < 128 * 64; idx += 256) {
        int n = idx & 127, k2 = idx >> 7;
        float w0 = W[(2 * k2) * 128 + n];
        float w1 = W[(2 * k2 + 1) * 128 + n];
        int byte = (n << 8) + ((k2 << 2) ^ ((n & 7) << 4));
        *(uint*)(dst + byte) = pack2(w0, w1);
    }
}

// ---------------- layer 0: aggregate x (4ch), then transform+LN ----------------

__global__ void __launch_bounds__(256) k_agg_x(
    const float* __restrict__ x, const int2* __restrict__ edata,
    const int* __restrict__ rp, const float* __restrict__ dinv,
    float* __restrict__ ax, int N)
{
    int tid = threadIdx.x;
    int ch = tid & 3, es = (tid >> 2) & 3;
    int node = blockIdx.x * 16 + (tid >> 4);
    if (node >= N) return;
    int e0 = rp[node], e1 = rp[node + 1];
    float acc = 0.f;
    for (int e = e0 + es; e < e1; e += 4) {
        int2 ed = edata[e];
        acc = fmaf(__int_as_float(ed.y), x[(size_t)ed.x * 4 + ch], acc);
    }
    acc += __shfl_xor(acc, 4);
    acc += __shfl_xor(acc, 8);
    if (es == 0) {
        float di = dinv[node];
        acc = fmaf(di * di, x[(size_t)node * 4 + ch], acc);
        ax[(size_t)node * 4 + ch] = acc;
    }
}

__global__ void __launch_bounds__(256) k_l0_ln(
    const float* __restrict__ ax, const float* __restrict__ W0,
    const float* __restrict__ b0, const float* __restrict__ g0,
    const float* __restrict__ be0, uint* __restrict__ hA, int N)
{
    __shared__ float s[896];
    int tid = threadIdx.x;
    for (int i = tid; i < 896; i += 256) {
        float v;
        if (i < 512) v = W0[i];
        else if (i < 640) v = b0[i - 512];
        else if (i < 768) v = g0[i - 640];
        else v = be0[i - 768];
        s[i] = v;
    }
    __syncthreads();
    int lane = tid & 63;
    int node = blockIdx.x * 4 + (tid >> 6);
    if (node >= N) return;
    float4 a = *(const float4*)&ax[(size_t)node * 4];
    int c0 = 2 * lane, c1 = c0 + 1;
    float v0 = a.x * s[c0] + a.y * s[128 + c0] + a.z * s[256 + c0] + a.w * s[384 + c0] + s[512 + c0];
    float v1 = a.x * s[c1] + a.y * s[128 + c1] + a.z * s[256 + c1] + a.w * s[384 + c1] + s[512 + c1];
    v0 = fmaxf(v0, 0.f); v1 = fmaxf(v1, 0.f);
    float s1 = v0 + v1, s2 = v0 * v0 + v1 * v1;
#pragma unroll
    for (int off = 32; off; off >>= 1) { s1 += __shfl_xor(s1, off); s2 += __shfl_xor(s2, off); }
    float mu = s1 * (1.f / 128.f), var = s2 * (1.f / 128.f) - mu * mu;
    float r = rsqrtf(var + EPSV);
    float o0 = (v0 - mu) * r * s[640 + c0] + s[768 + c0];
    float o1 = (v1 - mu) * r * s[640 + c1] + s[768 + c1];
    hA[(size_t)node * 64 + lane] = pack2(o0, o1);
}

// ---------------- fused agg -> @W -> bias -> relu -> LN ----------------
// Block = 4 waves x 4 nodes/wave (same gather shape as the proven k_agg_ln),
// 16-row MFMA m-tile, W pre-swizzled bf16 in global (L2-resident).

__global__ void __launch_bounds__(256) k_aggw(
    const uint* __restrict__ tmp,   // N x 64 (bf16x2) gather table
    const int2* __restrict__ edata, const int* __restrict__ rp,
    const float* __restrict__ dinv, const ushort* __restrict__ Wp,
    const float* __restrict__ bias, const float* __restrict__ gamma,
    const float* __restrict__ beta, uint* __restrict__ outp, int N)
{
    __shared__ char Asw[16 * 256];      // 4 KB agg tile, XOR-swizzled
    __shared__ uint Cst[16 * 64];       // 4 KB output staging
    __shared__ float red[128];          // row partials: [row*4+wv], s2 at +64
    int tid = threadIdx.x;
    int wv = tid >> 6, lane = tid & 63;
    int nbase = blockIdx.x * 16;

    // phase A: gather 4 nodes per wave (identical structure to k_agg_ln)
    for (int j = 0; j < 4; ++j) {
        int row = wv * 4 + j;
        int node = nbase + row;
        float ax = 0.f, ay = 0.f;
        if (node < N) {
            float di = dinv[node];
            uint v = tmp[(size_t)node * 64 + lane];
            ax = di * di * blo(v); ay = di * di * bhi(v);
            int e0 = rp[node], e1 = rp[node + 1];
            int e = e0;
            for (; e + 4 <= e1; e += 4) {
                long long p0 = __builtin_nontemporal_load((const long long*)&edata[e]);
                long long p1 = __builtin_nontemporal_load((const long long*)&edata[e + 1]);
                long long p2 = __builtin_nontemporal_load((const long long*)&edata[e + 2]);
                long long p3 = __builtin_nontemporal_load((const long long*)&edata[e + 3]);
                uint v0 = tmp[(size_t)(int)p0 * 64 + lane];
                uint v1 = tmp[(size_t)(int)p1 * 64 + lane];
                uint v2 = tmp[(size_t)(int)p2 * 64 + lane];
                uint v3 = tmp[(size_t)(int)p3 * 64 + lane];
                float n0 = __int_as_float((int)(p0 >> 32));
                float n1 = __int_as_float((int)(p1 >> 32));
                float n2 = __int_as_float((int)(p2 >> 32));
                float n3 = __int_as_float((int)(p3 >> 32));
                ax = fmaf(n0, blo(v0), ax); ay = fmaf(n0, bhi(v0), ay);
                ax = fmaf(n1, blo(v1), ax); ay = fmaf(n1, bhi(v1), ay);
                ax = fmaf(n2, blo(v2), ax); ay = fmaf(n2, bhi(v2), ay);
                ax = fmaf(n3, blo(v3), ax); ay = fmaf(n3, bhi(v3), ay);
            }
            for (; e < e1; ++e) {
                long long p0 = __builtin_nontemporal_load((const long long*)&edata[e]);
                uint v0 = tmp[(size_t)(int)p0 * 64 + lane];
                float n0 = __int_as_float((int)(p0 >> 32));
                ax = fmaf(n0, blo(v0), ax); ay = fmaf(n0, bhi(v0), ay);
            }
        }
        *(uint*)(Asw + row * 256 + ((lane * 4) ^ ((row & 7) << 4))) = pack2(ax, ay);
    }
    __syncthreads();

    // phase B: 16x128 @ 128x128 — wave wv computes n-tiles {2wv, 2wv+1}
    int m = lane & 15, g = lane >> 4;
    bf16x8 a[4];
    int aswz = (m & 7) << 4;
#pragma unroll
    for (int kk = 0; kk < 4; ++kk)
        a[kk] = *(const bf16x8*)(Asw + m * 256 + ((kk * 64 + g * 16) ^ aswz));

    f32x4 acc[2];
    acc[0] = (f32x4){0.f, 0.f, 0.f, 0.f};
    acc[1] = (f32x4){0.f, 0.f, 0.f, 0.f};
#pragma unroll
    for (int t2 = 0; t2 < 2; ++t2) {
        int n = m + (2 * wv + t2) * 16;
        const char* wb = (const char*)Wp + (n << 8);
        int swz = (n & 7) << 4;
#pragma unroll
        for (int kk = 0; kk < 4; ++kk) {
            bf16x8 b = *(const bf16x8*)(wb + ((kk * 64 + g * 16) ^ swz));
            acc[t2] = __builtin_amdgcn_mfma_f32_16x16x32_bf16(a[kk], b, acc[t2], 0, 0, 0);
        }
    }

    // bias + relu, per-row partial sums (16-lane groups hold one row's 32 cols)
    float bc0 = bias[m + (2 * wv) * 16];
    float bc1 = bias[m + (2 * wv + 1) * 16];
    float vals0[4], vals1[4];
#pragma unroll
    for (int q = 0; q < 4; ++q) {
        float v0 = fmaxf(acc[0][q] + bc0, 0.f);
        float v1 = fmaxf(acc[1][q] + bc1, 0.f);
        vals0[q] = v0; vals1[q] = v1;
        float s1 = v0 + v1, s2 = v0 * v0 + v1 * v1;
#pragma unroll
        for (int off = 1; off < 16; off <<= 1) { s1 += __shfl_xor(s1, off); s2 += __shfl_xor(s2, off); }
        if (m == 0) {
            red[(g * 4 + q) * 4 + wv] = s1;
            red[64 + (g * 4 + q) * 4 + wv] = s2;
        }
    }
    __syncthreads();

    // phase C: LN, write bf16 to staging
    float gc0 = gamma[m + (2 * wv) * 16],  gc1 = gamma[m + (2 * wv + 1) * 16];
    float be0 = beta[m + (2 * wv) * 16],   be1 = beta[m + (2 * wv + 1) * 16];
#pragma unroll
    for (int q = 0; q < 4; ++q) {
        int row = g * 4 + q;
        float s1 = red[row * 4] + red[row * 4 + 1] + red[row * 4 + 2] + red[row * 4 + 3];
        float s2 = red[64 + row * 4] + red[64 + row * 4 + 1] + red[64 + row * 4 + 2] + red[64 + row * 4 + 3];
        float mu = s1 * (1.f / 128.f), var = s2 * (1.f / 128.f) - mu * mu;
        float r = rsqrtf(var + EPSV);
        ((ushort*)Cst)[row * 128 + m + (2 * wv) * 16]     = (ushort)bf16_rne((vals0[q] - mu) * r * gc0 + be0);
        ((ushort*)Cst)[row * 128 + m + (2 * wv + 1) * 16] = (ushort)bf16_rne((vals1[q] - mu) * r * gc1 + be1);
    }
    __syncthreads();

    // phase D: coalesced store
#pragma unroll
    for (int rr = 0; rr < 4; ++rr) {
        int row = rr * 4 + wv;
        int node = nbase + row;
        if (node < N)
            outp[(size_t)node * 64 + lane] = Cst[row * 64 + lane];
    }
}

// ---------------- pooling (bf16 input) ----------------

__global__ void __launch_bounds__(64) k_pool(
    const uint* __restrict__ h, const int* __restrict__ batch,
    float* __restrict__ featsum, float* __restrict__ cntg, int N)
{
    int g = blockIdx.x / SLICES, s = blockIdx.x % SLICES;
    int lane = threadIdx.x;
    int lo = 0, hi = N;
    while (lo < hi) { int m = (lo + hi) >> 1; if (batch[m] < g) lo = m + 1; else hi = m; }
    int start = lo;
    hi = N;
    while (lo < hi) { int m = (lo + hi) >> 1; if (batch[m] < g + 1) lo = m + 1; else hi = m; }
    int end = lo;
    int len = end - start;
    if (s == 0 && lane == 0) cntg[g] = (float)len;
    int per = (len + SLICES - 1) / SLICES;
    int a = start + s * per, b = min(a + per, end);
    float accx = 0.f, accy = 0.f;
    for (int i = a; i < b; ++i) {
        uint v = h[(size_t)i * 64 + lane];
        accx += blo(v); accy += bhi(v);
    }
    atomicAdd(&featsum[g * 128 + 2 * lane], accx);
    atomicAdd(&featsum[g * 128 + 2 * lane + 1], accy);
}

// ---------------- FC head (fp32) ----------------

__global__ void __launch_bounds__(256) k_fc1(const float* __restrict__ featsum,
        const float* __restrict__ cntg, const float* __restrict__ W,
        const float* __restrict__ b, float* __restrict__ z1) {
    int g = blockIdx.x, tid = threadIdx.x;
    __shared__ float fr[128];
    if (tid < 128) fr[tid] = featsum[g * 128 + tid] / fmaxf(cntg[g], 1.f);
    __syncthreads();
    float acc[4];
#pragma unroll
    for (int j = 0; j < 4; j++) acc[j] = b[tid + 256 * j];
    for (int k = 0; k < 128; ++k) {
        float f = fr[k];
#pragma unroll
        for (int j = 0; j < 4; j++) acc[j] = fmaf(f, W[k * 1024 + tid + 256 * j], acc[j]);
    }
    float s1 = 0.f, s2 = 0.f;
#pragma unroll
    for (int j = 0; j < 4; j++) { s1 += acc[j]; s2 += acc[j] * acc[j]; }
    for (int off = 32; off; off >>= 1) { s1 += __shfl_xor(s1, off); s2 += __shfl_xor(s2, off); }
    __shared__ float red[8];
    int w = tid >> 6;
    if ((tid & 63) == 0) { red[w] = s1; red[w + 4] = s2; }
    __syncthreads();
    s1 = red[0] + red[1] + red[2] + red[3];
    s2 = red[4] + red[5] + red[6] + red[7];
    float mu = s1 * (1.f / 1024.f), var = s2 * (1.f / 1024.f) - mu * mu;
    float r = rsqrtf(var + EPSV);
#pragma unroll
    for (int j = 0; j < 4; j++)
        z1[g * 1024 + tid + 256 * j] = fmaxf((acc[j] - mu) * r, 0.f);
}

__global__ void __launch_bounds__(256) k_fc2(const float* __restrict__ z1,
        const float* __restrict__ W, const float* __restrict__ b, float* __restrict__ z2) {
    int g = blockIdx.x, tid = threadIdx.x;
    __shared__ float zr[1024];
    for (int i = tid; i < 1024; i += 256) zr[i] = z1[g * 1024 + i];
    __syncthreads();
    float acc = b[tid];
#pragma unroll 8
    for (int k = 0; k < 1024; ++k) acc = fmaf(zr[k], W[k * 256 + tid], acc);
    float s1 = acc, s2 = acc * acc;
    for (int off = 32; off; off >>= 1) { s1 += __shfl_xor(s1, off); s2 += __shfl_xor(s2, off); }
    __shared__ float red[8];
    int w = tid >> 6;
    if ((tid & 63) == 0) { red[w] = s1; red[w + 4] = s2; }
    __syncthreads();
    s1 = red[0] + red[1] + red[2] + red[3];
    s2 = red[4] + red[5] + red[6] + red[7];
    float mu = s1 * (1.f / 256.f), var = s2 * (1.f / 256.f) - mu * mu;
    float r = rsqrtf(var + EPSV);
    z2[g * 256 + tid] = fmaxf((acc - mu) * r, 0.f);
}

__global__ void k_fc3(const float* __restrict__ z2, const float* __restrict__ W,
                      const float* __restrict__ b, float* __restrict__ out) {
    int t = threadIdx.x;
    int g = t >> 2, o = t & 3;
    float acc = b[o];
#pragma unroll 8
    for (int k = 0; k < 256; ++k) acc = fmaf(z2[g * 256 + k], W[k * 4 + o], acc);
    out[t] = acc;
}

// ---------------- launch ----------------

extern "C" void kernel_launch(void* const* d_in, const int* in_sizes, int n_in,
                              void* d_out, int out_size, void* d_ws, size_t ws_size,
                              hipStream_t stream) {
    const float* x    = (const float*)d_in[0];
    const int*   ei   = (const int*)d_in[1];
    const int*   batch= (const int*)d_in[2];
    const float* Wl[4]  = { (const float*)d_in[3], (const float*)d_in[7],  (const float*)d_in[11], (const float*)d_in[15] };
    const float* bl[4]  = { (const float*)d_in[4], (const float*)d_in[8],  (const float*)d_in[12], (const float*)d_in[16] };
    const float* gl[4]  = { (const float*)d_in[5], (const float*)d_in[9],  (const float*)d_in[13], (const float*)d_in[17] };
    const float* bel[4] = { (const float*)d_in[6], (const float*)d_in[10], (const float*)d_in[14], (const float*)d_in[18] };
    const float* fcW1 = (const float*)d_in[19];
    const float* fcb1 = (const float*)d_in[20];
    const float* fcW2 = (const float*)d_in[21];
    const float* fcb2 = (const float*)d_in[22];
    const float* fcW3 = (const float*)d_in[23];
    const float* fcb3 = (const float*)d_in[24];
    float* out = (float*)d_out;

    const int N = in_sizes[2];
    const int E = in_sizes[1] / 2;

    char* w = (char*)d_ws;
    auto alloc = [&](size_t bytes) -> char* {
        char* p = w; w += (bytes + 255) & ~(size_t)255; return p;
    };
    uint*   hA      = (uint*)  alloc((size_t)N * 64 * 4);   // bf16 N x 128
    uint*   hB      = (uint*)  alloc((size_t)N * 64 * 4);
    float*  ax      = (float*) alloc((size_t)N * 4 * 4);
    int2*   edata   = (int2*)  alloc((size_t)E * 8);
    int*    rp      = (int*)   alloc((size_t)(N + 1) * 4);
    int*    cursor  = (int*)   alloc((size_t)N * 4);
    int*    cntI    = (int*)   alloc((size_t)N * 4);
    float*  dinv    = (float*) alloc((size_t)N * 4);
    int*    partial = (int*)   alloc(64 * 4);
    ushort* Wp      = (ushort*)alloc(3 * 128 * 128 * 2);
    float*  featsum = (float*) alloc(NGRAPH * HIDC * 4);
    float*  cntg    = (float*) alloc(NGRAPH * 4);
    float*  z1      = (float*) alloc(NGRAPH * 1024 * 4);
    float*  z2      = (float*) alloc(NGRAPH * 256 * 4);

    const int NCH = (N + 2047) / 2048;

    hipMemsetAsync(cntI, 0, (size_t)N * 4, stream);
    hipMemsetAsync(featsum, 0, NGRAPH * HIDC * 4, stream);

    int egrid = (E + 255) / 256;
    int ngrid = (N + 255) / 256;

    k_count<<<egrid, 256, 0, stream>>>(ei, E, cntI);
    k_scan1<<<NCH, 256, 0, stream>>>(cntI, rp, partial, N);
    k_scan3<<<ngrid, 256, 0, stream>>>(rp, cursor, partial, cntI, dinv, N, E, NCH);
    k_fill<<<egrid, 256, 0, stream>>>(ei, E, dinv, cursor, edata);
    k_prepW<<<3, 256, 0, stream>>>(Wl[1], Wl[2], Wl[3], Wp);

    // layer 0: agg(x) then transform+bias+relu+LN  -> hA
    k_agg_x<<<(N + 15) / 16, 256, 0, stream>>>(x, edata, rp, dinv, ax, N);
    k_l0_ln<<<(N + 3) / 4, 256, 0, stream>>>(ax, Wl[0], bl[0], gl[0], bel[0], hA, N);

    // layers 1..3: fused agg -> @W -> bias -> relu -> LN (ping-pong hA/hB)
    const int fgrid = (N + 15) / 16;
    uint* tin = hA;
    uint* tout = hB;
    for (int L = 1; L < 4; ++L) {
        k_aggw<<<fgrid, 256, 0, stream>>>(
            tin, edata, rp, dinv, Wp + (L - 1) * 128 * 128,
            bl[L], gl[L], bel[L], tout, N);
        uint* t = tin; tin = tout; tout = t;
    }
    // result in tin (hB)

    k_pool<<<NGRAPH * SLICES, 64, 0, stream>>>(tin, batch, featsum, cntg, N);
    k_fc1<<<NGRAPH, 256, 0, stream>>>(featsum, cntg, fcW1, fcb1, z1);
    k_fc2<<<NGRAPH, 256, 0, stream>>>(z1, fcW2, fcb2, z2);
    k_fc3<<<1, 256, 0, stream>>>(z2, fcW3, fcb3, out);
}

// Round 7
// 599.999 us; speedup vs baseline: 1.4528x; 1.0900x over previous
//
#include <hip/hip_runtime.h>

#define HIDC 128
#define NGRAPH 64
#define EPSV 1e-5f

typedef __attribute__((ext_vector_type(8))) short bf16x8;
typedef __attribute__((ext_vector_type(4))) float f32x4;

__device__ inline uint bf16_rne(float f) {
    uint u = __float_as_uint(f);
    return (u + 0x7fffu + ((u >> 16) & 1u)) >> 16;
}
__device__ inline uint pack2(float a, float b) { return bf16_rne(a) | (bf16_rne(b) << 16); }
__device__ inline float blo(uint v) { return __uint_as_float(v << 16); }
__device__ inline float bhi(uint v) { return __uint_as_float(v & 0xffff0000u); }

// ---------------- init: zero cntI + featsum, prep W (bf16 swizzled) ----------------

__global__ void k_init(int* __restrict__ cntI, float* __restrict__ featsum, int N,
                       const float* __restrict__ W1, const float* __restrict__ W2,
                       const float* __restrict__ W3, ushort* __restrict__ Wp,
                       int ngrid) {
    int b = blockIdx.x;
    if (b < ngrid) {
        int i = b * 256 + threadIdx.x;
        if (i < N) cntI[i] = 0;
        if (i < NGRAPH * HIDC) featsum[i] = 0.f;
    } else {
        int w = b - ngrid;   // 0..2
        const float* W = (w == 0) ? W1 : (w == 1) ? W2 : W3;
        char* dst = (char*)(Wp + w * 128 * 128);
        for (int idx = threadIdx.x; idx < 128 * 64; idx += 256) {
            int n = idx & 127, k2 = idx >> 7;
            float w0 = W[(2 * k2) * 128 + n];
            float w1 = W[(2 * k2 + 1) * 128 + n];
            int byte = (n << 8) + ((k2 << 2) ^ ((n & 7) << 4));
            *(uint*)(dst + byte) = pack2(w0, w1);
        }
    }
}

// ---------------- CSR build ----------------

__global__ void k_count(const int* __restrict__ ei, int E, int* __restrict__ cnt) {
    int e2 = (blockIdx.x * blockDim.x + threadIdx.x) * 2;
    if (e2 + 1 < E) {
        int2 d = *(const int2*)&ei[E + e2];
        atomicAdd(&cnt[d.x], 1);
        atomicAdd(&cnt[d.y], 1);
    } else if (e2 < E) {
        atomicAdd(&cnt[ei[E + e2]], 1);
    }
}

__global__ void k_scan1(const int* __restrict__ cnt, int* __restrict__ rp,
                        int* __restrict__ partial, int N) {
    const int tid = threadIdx.x;
    int base = blockIdx.x * 2048 + tid * 8;
    int v[8], pre[8];
    int tot = 0;
#pragma unroll
    for (int j = 0; j < 8; j++) {
        int idx = base + j;
        v[j] = (idx < N) ? cnt[idx] : 0;
        pre[j] = tot; tot += v[j];
    }
    __shared__ int ls[256];
    ls[tid] = tot; __syncthreads();
    for (int off = 1; off < 256; off <<= 1) {
        int add = (tid >= off) ? ls[tid - off] : 0;
        __syncthreads();
        ls[tid] += add;
        __syncthreads();
    }
    int excl = ls[tid] - tot;
#pragma unroll
    for (int j = 0; j < 8; j++) {
        int idx = base + j;
        if (idx < N) rp[idx] = excl + pre[j];
    }
    if (tid == 255) partial[blockIdx.x] = ls[255];
}

__global__ void k_scan3(int* __restrict__ rp, int* __restrict__ cursor,
                        const int* __restrict__ partial, const int* __restrict__ cnt,
                        float* __restrict__ dinv, int N, int E, int NCH) {
    __shared__ int soff;
    int tid = threadIdx.x;
    int chunk = blockIdx.x >> 3;              // 2048 / 256
    if (tid < 64) {
        int v = (tid < NCH && tid < chunk) ? partial[tid] : 0;
        for (int off = 1; off < 64; off <<= 1) v += __shfl_xor(v, off);
        if (tid == 0) soff = v;
    }
    __syncthreads();
    int i = blockIdx.x * blockDim.x + tid;
    if (i < N) {
        int v = rp[i] + soff;
        rp[i] = v; cursor[i] = v;
        dinv[i] = rsqrtf((float)(cnt[i] + 1));   // +1 self loop
    }
    if (i == 0) rp[N] = E;
}

__global__ void k_fill(const int* __restrict__ ei, int E, const float* __restrict__ dinv,
                       int* __restrict__ cursor, int2* __restrict__ edata) {
    int e2 = (blockIdx.x * blockDim.x + threadIdx.x) * 2;
    if (e2 + 1 < E) {
        int2 s2 = *(const int2*)&ei[e2];
        int2 d2 = *(const int2*)&ei[E + e2];
        int p0 = atomicAdd(&cursor[d2.x], 1);
        edata[p0] = make_int2(s2.x, __float_as_int(dinv[s2.x] * dinv[d2.x]));
        int p1 = atomicAdd(&cursor[d2.y], 1);
        edata[p1] = make_int2(s2.y, __float_as_int(dinv[s2.y] * dinv[d2.y]));
    } else if (e2 < E) {
        int s = ei[e2], d = ei[E + e2];
        int p = atomicAdd(&cursor[d], 1);
        edata[p] = make_int2(s, __float_as_int(dinv[s] * dinv[d]));
    }
}

// ---------------- layer 0 fused: agg(x) -> @W0 -> bias -> relu -> LN ----------------
// 16 threads/node (ch 4 x edge-slice 4); shfl redistribution; per-lane 8-ch transform.

__global__ void __launch_bounds__(256) k_l0(
    const float* __restrict__ x, const int2* __restrict__ edata,
    const int* __restrict__ rp, const float* __restrict__ dinv,
    const float* __restrict__ W0, const float* __restrict__ b0,
    const float* __restrict__ g0, const float* __restrict__ be0,
    uint* __restrict__ hA, int N)
{
    __shared__ float s[896];   // W0 512 | b 128 | g 128 | be 128
    int tid = threadIdx.x;
    for (int i = tid; i < 896; i += 256) {
        float v;
        if (i < 512) v = W0[i];
        else if (i < 640) v = b0[i - 512];
        else if (i < 768) v = g0[i - 640];
        else v = be0[i - 768];
        s[i] = v;
    }
    __syncthreads();

    int lane = tid & 63;
    int wv = tid >> 6;
    int ch = lane & 3, es = (lane >> 2) & 3;
    int node = blockIdx.x * 16 + wv * 4 + (lane >> 4);
    bool valid = (node < N);

    // gather
    float acc = 0.f;
    if (valid) {
        int e0 = rp[node], e1 = rp[node + 1];
        for (int e = e0 + es; e < e1; e += 4) {
            int2 ed = edata[e];
            acc = fmaf(__int_as_float(ed.y), x[(size_t)ed.x * 4 + ch], acc);
        }
    }
    acc += __shfl_xor(acc, 4);
    acc += __shfl_xor(acc, 8);
    if (valid && es == 0) {
        float di = dinv[node];
        acc = fmaf(di * di, x[(size_t)node * 4 + ch], acc);
    }
    // redistribute ax[0..3] to all 16 lanes of the node
    int base = lane & ~15;
    float ax0 = __shfl(acc, base + 0);
    float ax1 = __shfl(acc, base + 1);
    float ax2 = __shfl(acc, base + 2);
    float ax3 = __shfl(acc, base + 3);

    // transform: 8 channels per lane
    int t = lane & 15;
    int c0 = t * 8;
    float v[8];
    float s1 = 0.f, s2 = 0.f;
#pragma unroll
    for (int j = 0; j < 8; ++j) {
        int c = c0 + j;
        float vv = ax0 * s[c] + ax1 * s[128 + c] + ax2 * s[256 + c] + ax3 * s[384 + c] + s[512 + c];
        vv = fmaxf(vv, 0.f);
        v[j] = vv; s1 += vv; s2 += vv * vv;
    }
#pragma unroll
    for (int off = 1; off < 16; off <<= 1) { s1 += __shfl_xor(s1, off); s2 += __shfl_xor(s2, off); }
    float mu = s1 * (1.f / 128.f), var = s2 * (1.f / 128.f) - mu * mu;
    float r = rsqrtf(var + EPSV);
    if (valid) {
        uint4 o;
        o.x = pack2((v[0] - mu) * r * s[640 + c0 + 0] + s[768 + c0 + 0],
                    (v[1] - mu) * r * s[640 + c0 + 1] + s[768 + c0 + 1]);
        o.y = pack2((v[2] - mu) * r * s[640 + c0 + 2] + s[768 + c0 + 2],
                    (v[3] - mu) * r * s[640 + c0 + 3] + s[768 + c0 + 3]);
        o.z = pack2((v[4] - mu) * r * s[640 + c0 + 4] + s[768 + c0 + 4],
                    (v[5] - mu) * r * s[640 + c0 + 5] + s[768 + c0 + 5]);
        o.w = pack2((v[6] - mu) * r * s[640 + c0 + 6] + s[768 + c0 + 6],
                    (v[7] - mu) * r * s[640 + c0 + 7] + s[768 + c0 + 7]);
        *(uint4*)&hA[(size_t)node * 64 + t * 4] = o;
    }
}

// ---------------- fused agg -> @W -> bias -> relu -> LN (+ optional pool) ----------------

__global__ void __launch_bounds__(256) k_aggw(
    const uint* __restrict__ tmp,   // N x 64 (bf16x2) gather table
    const int2* __restrict__ edata, const int* __restrict__ rp,
    const float* __restrict__ dinv, const ushort* __restrict__ Wp,
    const float* __restrict__ bias, const float* __restrict__ gamma,
    const float* __restrict__ beta, uint* __restrict__ outp, int N,
    float* __restrict__ featsum, const int* __restrict__ batch)
{
    __shared__ char Asw[16 * 256];      // 4 KB agg tile, XOR-swizzled
    __shared__ uint Cst[16 * 64];       // 4 KB output staging
    __shared__ float red[128];
    __shared__ int bi[16];
    int tid = threadIdx.x;
    int wv = tid >> 6, lane = tid & 63;
    int nbase = blockIdx.x * 16;

    // phase A: gather 4 nodes per wave
    for (int j = 0; j < 4; ++j) {
        int row = wv * 4 + j;
        int node = nbase + row;
        float ax = 0.f, ay = 0.f;
        if (node < N) {
            float di = dinv[node];
            uint v = tmp[(size_t)node * 64 + lane];
            ax = di * di * blo(v); ay = di * di * bhi(v);
            int e0 = rp[node], e1 = rp[node + 1];
            int e = e0;
            for (; e + 4 <= e1; e += 4) {
                long long p0 = __builtin_nontemporal_load((const long long*)&edata[e]);
                long long p1 = __builtin_nontemporal_load((const long long*)&edata[e + 1]);
                long long p2 = __builtin_nontemporal_load((const long long*)&edata[e + 2]);
                long long p3 = __builtin_nontemporal_load((const long long*)&edata[e + 3]);
                uint v0 = tmp[(size_t)(int)p0 * 64 + lane];
                uint v1 = tmp[(size_t)(int)p1 * 64 + lane];
                uint v2 = tmp[(size_t)(int)p2 * 64 + lane];
                uint v3 = tmp[(size_t)(int)p3 * 64 + lane];
                float n0 = __int_as_float((int)(p0 >> 32));
                float n1 = __int_as_float((int)(p1 >> 32));
                float n2 = __int_as_float((int)(p2 >> 32));
                float n3 = __int_as_float((int)(p3 >> 32));
                ax = fmaf(n0, blo(v0), ax); ay = fmaf(n0, bhi(v0), ay);
                ax = fmaf(n1, blo(v1), ax); ay = fmaf(n1, bhi(v1), ay);
                ax = fmaf(n2, blo(v2), ax); ay = fmaf(n2, bhi(v2), ay);
                ax = fmaf(n3, blo(v3), ax); ay = fmaf(n3, bhi(v3), ay);
            }
            for (; e < e1; ++e) {
                long long p0 = __builtin_nontemporal_load((const long long*)&edata[e]);
                uint v0 = tmp[(size_t)(int)p0 * 64 + lane];
                float n0 = __int_as_float((int)(p0 >> 32));
                ax = fmaf(n0, blo(v0), ax); ay = fmaf(n0, bhi(v0), ay);
            }
        }
        *(uint*)(Asw + row * 256 + ((lane * 4) ^ ((row & 7) << 4))) = pack2(ax, ay);
    }
    __syncthreads();

    // phase B: 16x128 @ 128x128 — wave wv computes n-tiles {2wv, 2wv+1}
    int m = lane & 15, g = lane >> 4;
    bf16x8 a[4];
    int aswz = (m & 7) << 4;
#pragma unroll
    for (int kk = 0; kk < 4; ++kk)
        a[kk] = *(const bf16x8*)(Asw + m * 256 + ((kk * 64 + g * 16) ^ aswz));

    f32x4 acc[2];
    acc[0] = (f32x4){0.f, 0.f, 0.f, 0.f};
    acc[1] = (f32x4){0.f, 0.f, 0.f, 0.f};
#pragma unroll
    for (int t2 = 0; t2 < 2; ++t2) {
        int n = m + (2 * wv + t2) * 16;
        const char* wb = (const char*)Wp + (n << 8);
        int swz = (n & 7) << 4;
#pragma unroll
        for (int kk = 0; kk < 4; ++kk) {
            bf16x8 b = *(const bf16x8*)(wb + ((kk * 64 + g * 16) ^ swz));
            acc[t2] = __builtin_amdgcn_mfma_f32_16x16x32_bf16(a[kk], b, acc[t2], 0, 0, 0);
        }
    }

    // bias + relu, per-row partial sums
    float bc0 = bias[m + (2 * wv) * 16];
    float bc1 = bias[m + (2 * wv + 1) * 16];
    float vals0[4], vals1[4];
#pragma unroll
    for (int q = 0; q < 4; ++q) {
        float v0 = fmaxf(acc[0][q] + bc0, 0.f);
        float v1 = fmaxf(acc[1][q] + bc1, 0.f);
        vals0[q] = v0; vals1[q] = v1;
        float s1 = v0 + v1, s2 = v0 * v0 + v1 * v1;
#pragma unroll
        for (int off = 1; off < 16; off <<= 1) { s1 += __shfl_xor(s1, off); s2 += __shfl_xor(s2, off); }
        if (m == 0) {
            red[(g * 4 + q) * 4 + wv] = s1;
            red[64 + (g * 4 + q) * 4 + wv] = s2;
        }
    }
    __syncthreads();

    // phase C: LN, write bf16 to staging
    float gc0 = gamma[m + (2 * wv) * 16],  gc1 = gamma[m + (2 * wv + 1) * 16];
    float be0 = beta[m + (2 * wv) * 16],   be1 = beta[m + (2 * wv + 1) * 16];
#pragma unroll
    for (int q = 0; q < 4; ++q) {
        int row = g * 4 + q;
        float s1 = red[row * 4] + red[row * 4 + 1] + red[row * 4 + 2] + red[row * 4 + 3];
        float s2 = red[64 + row * 4] + red[64 + row * 4 + 1] + red[64 + row * 4 + 2] + red[64 + row * 4 + 3];
        float mu = s1 * (1.f / 128.f), var = s2 * (1.f / 128.f) - mu * mu;
        float r = rsqrtf(var + EPSV);
        ((ushort*)Cst)[row * 128 + m + (2 * wv) * 16]     = (ushort)bf16_rne((vals0[q] - mu) * r * gc0 + be0);
        ((ushort*)Cst)[row * 128 + m + (2 * wv + 1) * 16] = (ushort)bf16_rne((vals1[q] - mu) * r * gc1 + be1);
    }
    __syncthreads();

    // phase D: coalesced store
#pragma unroll
    for (int rr = 0; rr < 4; ++rr) {
        int row = rr * 4 + wv;
        int node = nbase + row;
        if (node < N)
            outp[(size_t)node * 64 + lane] = Cst[row * 64 + lane];
    }

    // phase E (last layer): per-graph pool reduction from staging
    if (featsum) {
        if (tid < 16) {
            int node = nbase + tid;
            bi[tid] = (node < N) ? batch[node] : -1;
        }
        __syncthreads();
        int gmin = 0x7fffffff, gmax = -1;
#pragma unroll
        for (int r2 = 0; r2 < 16; ++r2) {
            int b = bi[r2];
            if (b >= 0) { gmin = min(gmin, b); gmax = max(gmax, b); }
        }
        if (tid < 128 && gmax >= 0) {
            for (int gg = gmin; gg <= gmax; ++gg) {
                float sv = 0.f; int cnt = 0;
#pragma unroll
                for (int r2 = 0; r2 < 16; ++r2) {
                    if (bi[r2] == gg) {
                        uint u = Cst[r2 * 64 + (tid >> 1)];
                        sv += (tid & 1) ? bhi(u) : blo(u);
                        cnt++;
                    }
                }
                if (cnt) atomicAdd(&featsum[gg * 128 + tid], sv);
            }
        }
    }
}

// ---------------- FC head (fp32) ----------------

__global__ void __launch_bounds__(256) k_fc1(const float* __restrict__ featsum,
        const int* __restrict__ batch, int N, const float* __restrict__ W,
        const float* __restrict__ b, float* __restrict__ z1) {
    int g = blockIdx.x, tid = threadIdx.x;
    __shared__ float fr[128];
    __shared__ int cnts;
    if (tid == 0) {
        int lo = 0, hi = N;
        while (lo < hi) { int mm = (lo + hi) >> 1; if (batch[mm] < g) lo = mm + 1; else hi = mm; }
        int st = lo; hi = N;
        while (lo < hi) { int mm = (lo + hi) >> 1; if (batch[mm] < g + 1) lo = mm + 1; else hi = mm; }
        cnts = lo - st;
    }
    __syncthreads();
    float inv = 1.f / fmaxf((float)cnts, 1.f);
    if (tid < 128) fr[tid] = featsum[g * 128 + tid] * inv;
    __syncthreads();
    float acc[4];
#pragma unroll
    for (int j = 0; j < 4; j++) acc[j] = b[tid + 256 * j];
    for (int k = 0; k < 128; ++k) {
        float f = fr[k];
#pragma unroll
        for (int j = 0; j < 4; j++) acc[j] = fmaf(f, W[k * 1024 + tid + 256 * j], acc[j]);
    }
    float s1 = 0.f, s2 = 0.f;
#pragma unroll
    for (int j = 0; j < 4; j++) { s1 += acc[j]; s2 += acc[j] * acc[j]; }
    for (int off = 32; off; off >>= 1) { s1 += __shfl_xor(s1, off); s2 += __shfl_xor(s2, off); }
    __shared__ float red[8];
    int w = tid >> 6;
    if ((tid & 63) == 0) { red[w] = s1; red[w + 4] = s2; }
    __syncthreads();
    s1 = red[0] + red[1] + red[2] + red[3];
    s2 = red[4] + red[5] + red[6] + red[7];
    float mu = s1 * (1.f / 1024.f), var = s2 * (1.f / 1024.f) - mu * mu;
    float r = rsqrtf(var + EPSV);
#pragma unroll
    for (int j = 0; j < 4; j++)
        z1[g * 1024 + tid + 256 * j] = fmaxf((acc[j] - mu) * r, 0.f);
}

__global__ void __launch_bounds__(256) k_fc2(const float* __restrict__ z1,
        const float* __restrict__ W, const float* __restrict__ b, float* __restrict__ z2) {
    int g = blockIdx.x, tid = threadIdx.x;
    __shared__ float zr[1024];
    for (int i = tid; i < 1024; i += 256) zr[i] = z1[g * 1024 + i];
    __syncthreads();
    float acc = b[tid];
#pragma unroll 8
    for (int k = 0; k < 1024; ++k) acc = fmaf(zr[k], W[k * 256 + tid], acc);
    float s1 = acc, s2 = acc * acc;
    for (int off = 32; off; off >>= 1) { s1 += __shfl_xor(s1, off); s2 += __shfl_xor(s2, off); }
    __shared__ float red[8];
    int w = tid >> 6;
    if ((tid & 63) == 0) { red[w] = s1; red[w + 4] = s2; }
    __syncthreads();
    s1 = red[0] + red[1] + red[2] + red[3];
    s2 = red[4] + red[5] + red[6] + red[7];
    float mu = s1 * (1.f / 256.f), var = s2 * (1.f / 256.f) - mu * mu;
    float r = rsqrtf(var + EPSV);
    z2[g * 256 + tid] = fmaxf((acc - mu) * r, 0.f);
}

__global__ void k_fc3(const float* __restrict__ z2, const float* __restrict__ W,
                      const float* __restrict__ b, float* __restrict__ out) {
    int t = threadIdx.x;
    int g = t >> 2, o = t & 3;
    float acc = b[o];
#pragma unroll 8
    for (int k = 0; k < 256; ++k) acc = fmaf(z2[g * 256 + k], W[k * 4 + o], acc);
    out[t] = acc;
}

// ---------------- launch ----------------

extern "C" void kernel_launch(void* const* d_in, const int* in_sizes, int n_in,
                              void* d_out, int out_size, void* d_ws, size_t ws_size,
                              hipStream_t stream) {
    const float* x    = (const float*)d_in[0];
    const int*   ei   = (const int*)d_in[1];
    const int*   batch= (const int*)d_in[2];
    const float* Wl[4]  = { (const float*)d_in[3], (const float*)d_in[7],  (const float*)d_in[11], (const float*)d_in[15] };
    const float* bl[4]  = { (const float*)d_in[4], (const float*)d_in[8],  (const float*)d_in[12], (const float*)d_in[16] };
    const float* gl[4]  = { (const float*)d_in[5], (const float*)d_in[9],  (const float*)d_in[13], (const float*)d_in[17] };
    const float* bel[4] = { (const float*)d_in[6], (const float*)d_in[10], (const float*)d_in[14], (const float*)d_in[18] };
    const float* fcW1 = (const float*)d_in[19];
    const float* fcb1 = (const float*)d_in[20];
    const float* fcW2 = (const float*)d_in[21];
    const float* fcb2 = (const float*)d_in[22];
    const float* fcW3 = (const float*)d_in[23];
    const float* fcb3 = (const float*)d_in[24];
    float* out = (float*)d_out;

    const int N = in_sizes[2];
    const int E = in_sizes[1] / 2;

    char* w = (char*)d_ws;
    auto alloc = [&](size_t bytes) -> char* {
        char* p = w; w += (bytes + 255) & ~(size_t)255; return p;
    };
    uint*   hA      = (uint*)  alloc((size_t)N * 64 * 4);   // bf16 N x 128
    uint*   hB      = (uint*)  alloc((size_t)N * 64 * 4);
    int2*   edata   = (int2*)  alloc((size_t)E * 8);
    int*    rp      = (int*)   alloc((size_t)(N + 1) * 4);
    int*    cursor  = (int*)   alloc((size_t)N * 4);
    int*    cntI    = (int*)   alloc((size_t)N * 4);
    float*  dinv    = (float*) alloc((size_t)N * 4);
    int*    partial = (int*)   alloc(64 * 4);
    ushort* Wp      = (ushort*)alloc(3 * 128 * 128 * 2);
    float*  featsum = (float*) alloc(NGRAPH * HIDC * 4);
    float*  z1      = (float*) alloc(NGRAPH * 1024 * 4);
    float*  z2      = (float*) alloc(NGRAPH * 256 * 4);

    const int NCH = (N + 2047) / 2048;
    int egrid2 = (E / 2 + 255) / 256;
    int ngrid = (N + 255) / 256;

    k_init<<<ngrid + 3, 256, 0, stream>>>(cntI, featsum, N, Wl[1], Wl[2], Wl[3], Wp, ngrid);
    k_count<<<egrid2, 256, 0, stream>>>(ei, E, cntI);
    k_scan1<<<NCH, 256, 0, stream>>>(cntI, rp, partial, N);
    k_scan3<<<ngrid, 256, 0, stream>>>(rp, cursor, partial, cntI, dinv, N, E, NCH);
    k_fill<<<egrid2, 256, 0, stream>>>(ei, E, dinv, cursor, edata);

    // layer 0 fused -> hA
    k_l0<<<(N + 15) / 16, 256, 0, stream>>>(x, edata, rp, dinv, Wl[0], bl[0], gl[0], bel[0], hA, N);

    // layers 1..3 fused (last one also pools)
    const int fgrid = (N + 15) / 16;
    uint* tin = hA;
    uint* tout = hB;
    for (int L = 1; L < 4; ++L) {
        k_aggw<<<fgrid, 256, 0, stream>>>(
            tin, edata, rp, dinv, Wp + (L - 1) * 128 * 128,
            bl[L], gl[L], bel[L], tout, N,
            (L == 3) ? featsum : nullptr, batch);
        uint* t = tin; tin = tout; tout = t;
    }

    k_fc1<<<NGRAPH, 256, 0, stream>>>(featsum, batch, N, fcW1, fcb1, z1);
    k_fc2<<<NGRAPH, 256, 0, stream>>>(z1, fcW2, fcb2, z2);
    k_fc3<<<1, 256, 0, stream>>>(z2, fcW3, fcb3, out);
}